// Round 10
// baseline (478.230 us; speedup 1.0000x reference)
//
#include <hip/hip_runtime.h>

// CustomFourierLayer: out[b,o] = sum_{i,k} coef[o,i,k] * f_k(x[b,i])
// R10: occupancy over tile size. Wave tile 64x64 (fr=2, fc=2, acc=64 AGPR),
// ~160 regs -> 3 waves/SIMD (__launch_bounds__(256,3)); 4-wave blocks put
// 1 wave/SIMD each, so each SIMD hosts 3 waves from 3 INDEPENDENT blocks
// (drifting phases -> real TLP). BM=64, BN=256, grid 1024 (m-major: the
// co-resident blocks share one (n,kb) B-stream). Phase = 4 i-cols, A in
// LDS (36.9KB dbuf), B frag-blobs global->VGPR, lgkm-only barrier/phase.

#define O_COLS 1024
#define I_DIM  1024
#define NF33   33
#define B_ROWS 4096

#define CW2_BYTES  ((size_t)32 * 2048 * 512 * 2)   // 64 MiB, f16 frag blobs
#define XT_OFF     (CW2_BYTES)                      // 16 MiB f32 x^T
#define XT_BYTES   ((size_t)I_DIM * B_ROWS * 4)
#define BK_OFF     (XT_OFF + XT_BYTES)              // 4 MiB f32 bk32[i][o]
#define BK_BYTES   ((size_t)I_DIM * O_COLS * 4)
#define BIAS_OFF   (BK_OFF + BK_BYTES)              // 4 KiB
#define PART_OFF   (BIAS_OFF + (1 << 20))           // 3 x 16 MiB partials
#define PART_BYTES ((size_t)B_ROWS * O_COLS * 4)
#define NEED_T1    (PART_OFF + 3 * PART_BYTES)
#define NEED_T2    (BIAS_OFF + 4096)

#define ASTR 36    // A LDS row stride in f16 (72 B; 2-way bank aliasing = free)

typedef _Float16 half8 __attribute__((ext_vector_type(8)));
typedef float f32x16 __attribute__((ext_vector_type(16)));
typedef float float4v __attribute__((ext_vector_type(4)));
union H8 { half8 v; _Float16 h[8]; };

#define BAR() asm volatile("s_waitcnt lgkmcnt(0)\n\ts_barrier" ::: "memory")

// source k in coef's [sin1..16 | cos1..16 | 1] layout for interleaved feature f
__device__ __forceinline__ int ksrc_of(int f) {
  return (f >= 32) ? 32 : ((f >> 1) + ((f & 1) ? 16 : 0));
}

// ---------------------------------------------------------------------------
// coef f32 [o][i][k] -> Cw2 f16 in 32x32x16 B-fragment blobs + bk32[i][o]=k32.
// Blob (ob32, i*2+kcl) = 1KB: lane l = kh*32 + (o&31) holds 8 f16 = features
// kcl*16 + kh*8 + e of column i, output col o = ob32*32 + (l&31). (validated)
// ---------------------------------------------------------------------------
__global__ __launch_bounds__(256)
void convert_coef2(const float* __restrict__ coef, _Float16* __restrict__ Cw2,
                   float* __restrict__ bk) {
  const int gtid = blockIdx.x * 256 + threadIdx.x;   // 1M threads
  const int o = gtid & 1023;
  const int i = gtid >> 10;

  const float* src = coef + (size_t)o * (I_DIM * NF33) + (size_t)i * NF33;
  float r[NF33];
#pragma unroll
  for (int k = 0; k < NF33; ++k) r[k] = src[k];

  const int ob32 = o >> 5;
#pragma unroll
  for (int kcl = 0; kcl < 2; ++kcl) {
#pragma unroll
    for (int kh = 0; kh < 2; ++kh) {
      H8 h;
#pragma unroll
      for (int e = 0; e < 8; ++e)
        h.h[e] = (_Float16)r[ksrc_of(kcl * 16 + kh * 8 + e)];
      const size_t blob = (size_t)ob32 * 2048 + (size_t)i * 2 + kcl;
      *(half8*)(Cw2 + blob * 512 + (kh * 32 + (o & 31)) * 8) = h.v;
    }
  }
  bk[(size_t)i * 1024 + o] = r[32];
}

// x [4096][1024] -> xT [1024][4096]
__global__ __launch_bounds__(256)
void transpose_x(const float* __restrict__ x, float* __restrict__ xT) {
  __shared__ float t[64][65];
  const int bi = blockIdx.x;   // I-tile 0..15
  const int bj = blockIdx.y;   // B-tile 0..63
  const int tx = threadIdx.x & 63, ty = threadIdx.x >> 6;
#pragma unroll
  for (int mq = 0; mq < 16; ++mq) {
    const int r = mq * 4 + ty;
    t[r][tx] = x[(size_t)(bj * 64 + r) * I_DIM + bi * 64 + tx];
  }
  __syncthreads();
#pragma unroll
  for (int mq = 0; mq < 16; ++mq) {
    const int r = mq * 4 + ty;
    xT[(size_t)(bi * 64 + r) * B_ROWS + bj * 64 + tx] = t[tx][r];
  }
}

// bias[o] = sum_i bk[i][o]
__global__ __launch_bounds__(256)
void bias_from_bk(const float* __restrict__ bk, float* __restrict__ bias) {
  const int o = blockIdx.x * 256 + threadIdx.x;
  float s0 = 0.f, s1 = 0.f, s2 = 0.f, s3 = 0.f;
  for (int i = 0; i < 1024; i += 4) {
    s0 += bk[(size_t)i * 1024 + o];
    s1 += bk[(size_t)(i + 1) * 1024 + o];
    s2 += bk[(size_t)(i + 2) * 1024 + o];
    s3 += bk[(size_t)(i + 3) * 1024 + o];
  }
  bias[o] = (s0 + s1) + (s2 + s3);
}

// out += p0 + p1 + p2
__global__ __launch_bounds__(256)
void reduce_parts(float* __restrict__ out, const float* __restrict__ p0,
                  const float* __restrict__ p1, const float* __restrict__ p2) {
  const size_t i = ((size_t)blockIdx.x * 256 + threadIdx.x) * 4;
  float4v a = *(float4v*)(out + i);
  float4v b = *(const float4v*)(p0 + i);
  float4v c = *(const float4v*)(p1 + i);
  float4v d = *(const float4v*)(p2 + i);
  *(float4v*)(out + i) = a + b + c + d;
}

// ---------------------------------------------------------------------------
// GEMM: 256 threads = 4 waves (wave = col-quarter wc), BM=64, BN=256,
// fr=2 x fc=2, 32x32x16 f16 MFMA. Phase = 4 i-columns; A-frags generated
// once per block into LDS (dbuf), ONE lgkm-only barrier per phase.
// 3 independent blocks per CU (3 waves/SIMD, each from a different block).
// ---------------------------------------------------------------------------
template <bool ATOMIC>
__global__ __launch_bounds__(256, 3)
void fourier_gemm8(const float* __restrict__ xT, const _Float16* __restrict__ Cw2,
                   const float* __restrict__ bias, float* __restrict__ out,
                   float* __restrict__ part) {
  __shared__ _Float16 As[2][4][64][ASTR];   // [buf][col][row][36], 36.9 KB

  const int tid = threadIdx.x, lane = tid & 63, wc = tid >> 6;

  const int bid = blockIdx.x;        // 1024 = 16 g x 64 m (m-major)
  const int g = bid & 15;
  const int m0 = (bid >> 4) * 64;
  const int n = g >> 2;
  const int kb = g & 3;
  const int o0 = n * 256;
  const int i0 = kb * 256;

  const int r32 = lane & 31, kh = lane >> 5;

  // A-gen assignment: thread owns (row = tid&63, col-in-phase = tid>>6)
  const int grow = tid & 63;
  const int gcol = tid >> 6;
  const float* pxa = xT + (size_t)(i0 + gcol) * B_ROWS + (m0 + grow);

  // B pointers: wave covers cols o0 + wc*64 + fc*32
  const _Float16* pb0 = Cw2 + ((size_t)(n * 8 + wc * 2 + 0) * 2048 + (size_t)i0 * 2) * 512 + lane * 8;
  const _Float16* pb1 = Cw2 + ((size_t)(n * 8 + wc * 2 + 1) * 2048 + (size_t)i0 * 2) * 512 + lane * 8;

  f32x16 acc[2][2];
#pragma unroll
  for (int fr = 0; fr < 2; ++fr)
#pragma unroll
    for (int fc = 0; fc < 2; ++fc)
#pragma unroll
      for (int q = 0; q < 16; ++q) acc[fr][fc][q] = 0.f;
  if (kb == 0) {
#pragma unroll
    for (int fc = 0; fc < 2; ++fc) {
      const float bv = bias[o0 + wc * 64 + fc * 32 + r32];
#pragma unroll
      for (int fr = 0; fr < 2; ++fr)
#pragma unroll
        for (int q = 0; q < 16; ++q) acc[fr][fc][q] = bv;
    }
  }

  // doubling-tree harmonics 1..16 of xv -> 32 interleaved [sin,cos] f16 at dst
  auto genH = [&](float xv, _Float16* dst) {
    float S[17], C[17];
    __sincosf(xv, &S[1], &C[1]);
    S[2] = 2.f * S[1] * C[1];  C[2] = fmaf(-2.f * S[1], S[1], 1.f);
    S[3] = S[2] * C[1] + C[2] * S[1];  C[3] = C[2] * C[1] - S[2] * S[1];
    S[4] = 2.f * S[2] * C[2];  C[4] = fmaf(-2.f * S[2], S[2], 1.f);
    S[5] = S[4] * C[1] + C[4] * S[1];  C[5] = C[4] * C[1] - S[4] * S[1];
    S[6] = S[4] * C[2] + C[4] * S[2];  C[6] = C[4] * C[2] - S[4] * S[2];
    S[7] = S[4] * C[3] + C[4] * S[3];  C[7] = C[4] * C[3] - S[4] * S[3];
    S[8] = 2.f * S[4] * C[4];  C[8] = fmaf(-2.f * S[4], S[4], 1.f);
#pragma unroll
    for (int k = 1; k < 8; ++k) {
      S[8 + k] = S[8] * C[k] + C[8] * S[k];
      C[8 + k] = C[8] * C[k] - S[8] * S[k];
    }
    S[16] = 2.f * S[8] * C[8];  C[16] = fmaf(-2.f * S[8], S[8], 1.f);
#pragma unroll
    for (int c4 = 0; c4 < 4; ++c4) {
      H8 h;
#pragma unroll
      for (int q = 0; q < 4; ++q) {
        const int k = c4 * 4 + q + 1;
        h.h[2 * q] = (_Float16)S[k];  h.h[2 * q + 1] = (_Float16)C[k];
      }
      *(half8*)(dst + c4 * 8) = h.v;
    }
  };

  half8 B0[4], B1[4];
  auto loadB = [&](half8 (&Bt)[4], int s) {   // s = local substep index
    const size_t base = (size_t)(s * 2) * 512;
    Bt[0] = *(const half8*)(pb0 + base);
    Bt[1] = *(const half8*)(pb0 + base + 512);
    Bt[2] = *(const half8*)(pb1 + base);
    Bt[3] = *(const half8*)(pb1 + base + 512);
  };

  auto compute = [&](int bn, int col, const half8 (&Bt)[4]) {
    half8 a_[2][2];
#pragma unroll
    for (int fr = 0; fr < 2; ++fr)
#pragma unroll
      for (int kcl = 0; kcl < 2; ++kcl)
        a_[fr][kcl] = *(const half8*)&As[bn][col][fr * 32 + r32][(kcl * 2 + kh) * 8];
#pragma unroll
    for (int kcl = 0; kcl < 2; ++kcl)
#pragma unroll
      for (int fr = 0; fr < 2; ++fr)
#pragma unroll
        for (int fc = 0; fc < 2; ++fc)
          acc[fr][fc] = __builtin_amdgcn_mfma_f32_32x32x16_f16(
              a_[fr][kcl], Bt[fc * 2 + kcl], acc[fr][fc], 0, 0, 0);
  };

  // prologue: A for phase 0 into buf0; x for phase 1; B for substep 0
  genH(pxa[0], &As[0][gcol][grow][0]);
  float xa = pxa[(size_t)4 * B_ROWS];
  loadB(B0, 0);
  BAR();

#pragma unroll 1
  for (int p = 0; p < 64; ++p) {
    const int buf = p & 1;
    const int s = 4 * p;
    // x for phase p+2 (OOB-safe: worst case lands inside d_ws)
    const float xan = pxa[(size_t)(s + 8) * B_ROWS];

    loadB(B1, s + 1);
    compute(buf, 0, B0);
    loadB(B0, s + 2);
    compute(buf, 1, B1);
    loadB(B1, s + 3);
    compute(buf, 2, B0);
    if (p < 63) loadB(B0, s + 4);
    genH(xa, &As[buf ^ 1][gcol][grow][0]);      // A for phase p+1
    compute(buf, 3, B1);
    BAR();                     // lgkm-only: B global loads stay in flight
    xa = xan;
  }

  // epilogue: C/D 32x32 layout col=lane&31, row=(q&3)+8*(q>>2)+4*(lane>>5)
  float* dst;
  if (ATOMIC) dst = out;
  else dst = (kb == 0) ? out : part + (size_t)(kb - 1) * (B_ROWS * O_COLS);
#pragma unroll
  for (int fr = 0; fr < 2; ++fr)
#pragma unroll
    for (int fc = 0; fc < 2; ++fc)
#pragma unroll
      for (int q = 0; q < 16; ++q) {
        const int row = m0 + fr * 32 + (q & 3) + 8 * (q >> 2) + 4 * kh;
        const int col = o0 + wc * 64 + fc * 32 + r32;
        if (ATOMIC) atomicAdd(&dst[(size_t)row * O_COLS + col], acc[fr][fc][q]);
        else dst[(size_t)row * O_COLS + col] = acc[fr][fc][q];
      }
}

// ---------------------------------------------------------------------------
// Fallback (ws too small): direct-coef 16x16x32 path (no workspace).
// ---------------------------------------------------------------------------
__global__ __launch_bounds__(512, 4)
void fourier_gemm_direct(const float* __restrict__ x, const float* __restrict__ coef,
                         float* __restrict__ out) {
  __shared__ _Float16 Asd[128 * 64];
  __shared__ _Float16 Bsd[128 * 64];

  const int tid = threadIdx.x;
  const int lane = tid & 63;
  const int wave = tid >> 6;
  const int wr = wave >> 1;
  const int wcd = wave & 1;

  const int bid = blockIdx.x;
  const int o0 = (bid & 7) * 128;
  const int kb = (bid >> 3) & 1;
  const int m0 = (bid >> 4) * 128;

  const int rowA = tid >> 3;
  const int cch = tid & 7;
  const int cswz = cch ^ (rowA & 7);
  const int n1 = tid >> 3;
  const int c1q = tid & 7;
  const int r16 = lane & 15;
  const int kq = lane >> 4;

  float4v acc[2][4];
#pragma unroll
  for (int fr = 0; fr < 2; ++fr)
#pragma unroll
    for (int fc = 0; fc < 4; ++fc) acc[fr][fc] = (float4v){0.f, 0.f, 0.f, 0.f};

  float s1a[8], c1a[8], sa[8], ca[8];
  float s1b[8], c1b[8], sb[8], cb[8];

  const float* xa_base = x + (size_t)(m0 + rowA) * I_DIM + (size_t)kb * 512 + cch * 8;
  const float* xb_base = xa_base + (size_t)64 * I_DIM;

#pragma unroll 1
  for (int ib2 = 0; ib2 < 8; ++ib2) {
    {
      const float* xa = xa_base + ib2 * 64;
      const float* xb = xb_base + ib2 * 64;
      float xva[8], xvb[8];
      *(float4*)&xva[0] = *(const float4*)(xa);
      *(float4*)&xva[4] = *(const float4*)(xa + 4);
      *(float4*)&xvb[0] = *(const float4*)(xb);
      *(float4*)&xvb[4] = *(const float4*)(xb + 4);
#pragma unroll
      for (int e = 0; e < 8; ++e) {
        __sincosf(xva[e], &s1a[e], &c1a[e]); sa[e] = s1a[e]; ca[e] = c1a[e];
        __sincosf(xvb[e], &s1b[e], &c1b[e]); sb[e] = s1b[e]; cb[e] = c1b[e];
      }
    }
#pragma unroll 1
    for (int f = 0; f < NF33; ++f) {
      H8 ha, hb;
      if (f == 32) {
#pragma unroll
        for (int e = 0; e < 8; ++e) { ha.h[e] = (_Float16)1.0f; hb.h[e] = (_Float16)1.0f; }
      } else if ((f & 1) == 0) {
#pragma unroll
        for (int e = 0; e < 8; ++e) { ha.h[e] = (_Float16)sa[e]; hb.h[e] = (_Float16)sb[e]; }
      } else {
#pragma unroll
        for (int e = 0; e < 8; ++e) { ha.h[e] = (_Float16)ca[e]; hb.h[e] = (_Float16)cb[e]; }
      }
      __syncthreads();
      {
        const int ks = ksrc_of(f);
        const int ibg = kb * 8 + ib2;
        H8 b1, b2;
#pragma unroll
        for (int e = 0; e < 8; ++e) {
          const size_t ii = (size_t)(ibg * 64 + c1q * 8 + e) * NF33 + ks;
          b1.h[e] = (_Float16)coef[(size_t)(o0 + n1) * (I_DIM * NF33) + ii];
          b2.h[e] = (_Float16)coef[(size_t)(o0 + n1 + 64) * (I_DIM * NF33) + ii];
        }
        const int cs = (c1q ^ (n1 & 7)) << 3;
        *(half8*)&Bsd[n1 * 64 + cs] = b1.v;
        *(half8*)&Bsd[(n1 + 64) * 64 + cs] = b2.v;
      }
      *(half8*)&Asd[rowA * 64 + cswz * 8] = ha.v;
      *(half8*)&Asd[(rowA + 64) * 64 + cswz * 8] = hb.v;
      if ((f & 1) && (f + 2 < NF33)) {
#pragma unroll
        for (int e = 0; e < 8; ++e) {
          float ns = sa[e] * c1a[e] + ca[e] * s1a[e];
          ca[e] = ca[e] * c1a[e] - sa[e] * s1a[e]; sa[e] = ns;
          float nsb = sb[e] * c1b[e] + cb[e] * s1b[e];
          cb[e] = cb[e] * c1b[e] - sb[e] * s1b[e]; sb[e] = nsb;
        }
      }
      __syncthreads();
#pragma unroll
      for (int ksu = 0; ksu < 2; ++ksu) {
        const int ch = ((ksu << 2) + kq) ^ (r16 & 7);
        half8 af[2], bf[4];
#pragma unroll
        for (int fr = 0; fr < 2; ++fr)
          af[fr] = *(const half8*)&Asd[(wr * 32 + fr * 16 + r16) * 64 + ch * 8];
#pragma unroll
        for (int fc = 0; fc < 4; ++fc)
          bf[fc] = *(const half8*)&Bsd[(wcd * 64 + fc * 16 + r16) * 64 + ch * 8];
#pragma unroll
        for (int fr = 0; fr < 2; ++fr)
#pragma unroll
          for (int fc = 0; fc < 4; ++fc)
            acc[fr][fc] = __builtin_amdgcn_mfma_f32_16x16x32_f16(
                af[fr], bf[fc], acc[fr][fc], 0, 0, 0);
      }
    }
  }
#pragma unroll
  for (int fr = 0; fr < 2; ++fr)
#pragma unroll
    for (int fc = 0; fc < 4; ++fc)
#pragma unroll
      for (int r = 0; r < 4; ++r) {
        const int row = m0 + wr * 32 + fr * 16 + kq * 4 + r;
        const int col = o0 + wcd * 64 + fc * 16 + r16;
        atomicAdd(&out[(size_t)row * O_COLS + col], acc[fr][fc][r]);
      }
}

extern "C" void kernel_launch(void* const* d_in, const int* in_sizes, int n_in,
                              void* d_out, int out_size, void* d_ws, size_t ws_size,
                              hipStream_t stream) {
  const float* x = (const float*)d_in[0];
  const float* coef = (const float*)d_in[1];
  float* out = (float*)d_out;

  if (ws_size >= NEED_T1 || ws_size >= NEED_T2) {
    _Float16* Cw2 = (_Float16*)d_ws;
    float* xT   = (float*)((char*)d_ws + XT_OFF);
    float* bk   = (float*)((char*)d_ws + BK_OFF);
    float* bias = (float*)((char*)d_ws + BIAS_OFF);
    convert_coef2<<<dim3(4096), dim3(256), 0, stream>>>(coef, Cw2, bk);
    transpose_x<<<dim3(16, 64), dim3(256), 0, stream>>>(x, xT);
    bias_from_bk<<<dim3(4), dim3(256), 0, stream>>>(bk, bias);
    if (ws_size >= NEED_T1) {
      float* part = (float*)((char*)d_ws + PART_OFF);
      fourier_gemm8<false><<<dim3(1024), dim3(256), 0, stream>>>(xT, Cw2, bias, out, part);
      reduce_parts<<<dim3(4096), dim3(256), 0, stream>>>(
          out, part, part + (size_t)B_ROWS * O_COLS, part + (size_t)2 * B_ROWS * O_COLS);
    } else {
      hipMemsetAsync(out, 0, (size_t)B_ROWS * O_COLS * sizeof(float), stream);
      fourier_gemm8<true><<<dim3(1024), dim3(256), 0, stream>>>(xT, Cw2, bias, out, nullptr);
    }
  } else {
    hipMemsetAsync(out, 0, (size_t)B_ROWS * O_COLS * sizeof(float), stream);
    fourier_gemm_direct<<<dim3(512), dim3(512), 0, stream>>>(x, coef, out);
  }
}

// Round 11
// 451.844 us; speedup vs baseline: 1.0584x; 1.0584x over previous
//
#include <hip/hip_runtime.h>

// CustomFourierLayer: out[b,o] = sum_{i,k} coef[o,i,k] * f_k(x[b,i])
// R11: R9 base + depth-2 software pipeline of A-frag ds_reads inside each
// phase (aX/aY named reg arrays; substep s+2's reads issued before substep
// s's MFMAs -> ds_read latency hidden under matrix work) + T5 setprio
// around each MFMA cluster. Geometry unchanged from R9: BM=128 BN=256,
// 4 waves, fr=4 fc=2, phase=4 i-cols, As dbuf 73.7KB, split-K x4.

#define O_COLS 1024
#define I_DIM  1024
#define NF33   33
#define B_ROWS 4096

#define CW2_BYTES  ((size_t)32 * 2048 * 512 * 2)   // 64 MiB, f16 frag blobs
#define XT_OFF     (CW2_BYTES)                      // 16 MiB f32 x^T
#define XT_BYTES   ((size_t)I_DIM * B_ROWS * 4)
#define BK_OFF     (XT_OFF + XT_BYTES)              // 4 MiB f32 bk32[i][o]
#define BK_BYTES   ((size_t)I_DIM * O_COLS * 4)
#define BIAS_OFF   (BK_OFF + BK_BYTES)              // 4 KiB
#define PART_OFF   (BIAS_OFF + (1 << 20))           // 3 x 16 MiB partials
#define PART_BYTES ((size_t)B_ROWS * O_COLS * 4)
#define NEED_T1    (PART_OFF + 3 * PART_BYTES)
#define NEED_T2    (BIAS_OFF + 4096)

#define ASTR 36    // A LDS row stride in f16 (72 B; 2-way bank aliasing = free)

typedef _Float16 half8 __attribute__((ext_vector_type(8)));
typedef float f32x16 __attribute__((ext_vector_type(16)));
typedef float float4v __attribute__((ext_vector_type(4)));
union H8 { half8 v; _Float16 h[8]; };

#define BAR() asm volatile("s_waitcnt lgkmcnt(0)\n\ts_barrier" ::: "memory")

// source k in coef's [sin1..16 | cos1..16 | 1] layout for interleaved feature f
__device__ __forceinline__ int ksrc_of(int f) {
  return (f >= 32) ? 32 : ((f >> 1) + ((f & 1) ? 16 : 0));
}

// ---------------------------------------------------------------------------
// coef f32 [o][i][k] -> Cw2 f16 in 32x32x16 B-fragment blobs + bk32[i][o]=k32.
// Blob (ob32, i*2+kcl) = 1KB: lane l = kh*32 + (o&31) holds 8 f16 = features
// kcl*16 + kh*8 + e of column i, output col o = ob32*32 + (l&31). (validated)
// ---------------------------------------------------------------------------
__global__ __launch_bounds__(256)
void convert_coef2(const float* __restrict__ coef, _Float16* __restrict__ Cw2,
                   float* __restrict__ bk) {
  const int gtid = blockIdx.x * 256 + threadIdx.x;   // 1M threads
  const int o = gtid & 1023;
  const int i = gtid >> 10;

  const float* src = coef + (size_t)o * (I_DIM * NF33) + (size_t)i * NF33;
  float r[NF33];
#pragma unroll
  for (int k = 0; k < NF33; ++k) r[k] = src[k];

  const int ob32 = o >> 5;
#pragma unroll
  for (int kcl = 0; kcl < 2; ++kcl) {
#pragma unroll
    for (int kh = 0; kh < 2; ++kh) {
      H8 h;
#pragma unroll
      for (int e = 0; e < 8; ++e)
        h.h[e] = (_Float16)r[ksrc_of(kcl * 16 + kh * 8 + e)];
      const size_t blob = (size_t)ob32 * 2048 + (size_t)i * 2 + kcl;
      *(half8*)(Cw2 + blob * 512 + (kh * 32 + (o & 31)) * 8) = h.v;
    }
  }
  bk[(size_t)i * 1024 + o] = r[32];
}

// x [4096][1024] -> xT [1024][4096]
__global__ __launch_bounds__(256)
void transpose_x(const float* __restrict__ x, float* __restrict__ xT) {
  __shared__ float t[64][65];
  const int bi = blockIdx.x;   // I-tile 0..15
  const int bj = blockIdx.y;   // B-tile 0..63
  const int tx = threadIdx.x & 63, ty = threadIdx.x >> 6;
#pragma unroll
  for (int mq = 0; mq < 16; ++mq) {
    const int r = mq * 4 + ty;
    t[r][tx] = x[(size_t)(bj * 64 + r) * I_DIM + bi * 64 + tx];
  }
  __syncthreads();
#pragma unroll
  for (int mq = 0; mq < 16; ++mq) {
    const int r = mq * 4 + ty;
    xT[(size_t)(bi * 64 + r) * B_ROWS + bj * 64 + tx] = t[tx][r];
  }
}

// bias[o] = sum_i bk[i][o]
__global__ __launch_bounds__(256)
void bias_from_bk(const float* __restrict__ bk, float* __restrict__ bias) {
  const int o = blockIdx.x * 256 + threadIdx.x;
  float s0 = 0.f, s1 = 0.f, s2 = 0.f, s3 = 0.f;
  for (int i = 0; i < 1024; i += 4) {
    s0 += bk[(size_t)i * 1024 + o];
    s1 += bk[(size_t)(i + 1) * 1024 + o];
    s2 += bk[(size_t)(i + 2) * 1024 + o];
    s3 += bk[(size_t)(i + 3) * 1024 + o];
  }
  bias[o] = (s0 + s1) + (s2 + s3);
}

// out += p0 + p1 + p2
__global__ __launch_bounds__(256)
void reduce_parts(float* __restrict__ out, const float* __restrict__ p0,
                  const float* __restrict__ p1, const float* __restrict__ p2) {
  const size_t i = ((size_t)blockIdx.x * 256 + threadIdx.x) * 4;
  float4v a = *(float4v*)(out + i);
  float4v b = *(const float4v*)(p0 + i);
  float4v c = *(const float4v*)(p1 + i);
  float4v d = *(const float4v*)(p2 + i);
  *(float4v*)(out + i) = a + b + c + d;
}

// ---------------------------------------------------------------------------
// GEMM: 256 threads = 4 waves (wave = col-quarter wc), BM=128, BN=256,
// fr=4 x fc=2, 32x32x16 f16 MFMA. Phase = 4 i-columns; A-frags generated
// once per block into LDS (dbuf), ONE lgkm-only barrier per phase.
// Depth-2 pipelined A ds_reads; setprio(1) around MFMA clusters.
// ---------------------------------------------------------------------------
template <bool ATOMIC>
__global__ __launch_bounds__(256, 2)
void fourier_gemm9(const float* __restrict__ xT, const _Float16* __restrict__ Cw2,
                   const float* __restrict__ bias, float* __restrict__ out,
                   float* __restrict__ part) {
  __shared__ _Float16 As[2][4][128][ASTR];   // [buf][col][row][36], 73.7 KB

  const int tid = threadIdx.x, lane = tid & 63, wc = tid >> 6;

  const int bid = blockIdx.x;        // 512 = 16 g x 32 m; co-resident pair shares g
  const int g = bid & 15;
  const int m0 = (bid >> 4) * 128;
  const int n = g >> 2;
  const int kb = g & 3;
  const int o0 = n * 256;
  const int i0 = kb * 256;

  const int r32 = lane & 31, kh = lane >> 5;

  // A-gen assignment: thread owns row grow, cols {gcw, gcw+2} of each phase
  const int grow = tid & 127;
  const int gcw = tid >> 7;          // 0 or 1
  const float* pxa = xT + (size_t)(i0 + gcw) * B_ROWS + (m0 + grow);
  const float* pxb = pxa + (size_t)2 * B_ROWS;

  // B pointers: wave covers cols o0 + wc*64 + fc*32
  const _Float16* pb0 = Cw2 + ((size_t)(n * 8 + wc * 2 + 0) * 2048 + (size_t)i0 * 2) * 512 + lane * 8;
  const _Float16* pb1 = Cw2 + ((size_t)(n * 8 + wc * 2 + 1) * 2048 + (size_t)i0 * 2) * 512 + lane * 8;

  f32x16 acc[4][2];
#pragma unroll
  for (int fr = 0; fr < 4; ++fr)
#pragma unroll
    for (int fc = 0; fc < 2; ++fc)
#pragma unroll
      for (int q = 0; q < 16; ++q) acc[fr][fc][q] = 0.f;
  if (kb == 0) {
#pragma unroll
    for (int fc = 0; fc < 2; ++fc) {
      const float bv = bias[o0 + wc * 64 + fc * 32 + r32];
#pragma unroll
      for (int fr = 0; fr < 4; ++fr)
#pragma unroll
        for (int q = 0; q < 16; ++q) acc[fr][fc][q] = bv;
    }
  }

  // doubling-tree harmonics 1..16 of xv -> 32 interleaved [sin,cos] f16 at dst
  auto genH = [&](float xv, _Float16* dst) {
    float S[17], C[17];
    __sincosf(xv, &S[1], &C[1]);
    S[2] = 2.f * S[1] * C[1];  C[2] = fmaf(-2.f * S[1], S[1], 1.f);
    S[3] = S[2] * C[1] + C[2] * S[1];  C[3] = C[2] * C[1] - S[2] * S[1];
    S[4] = 2.f * S[2] * C[2];  C[4] = fmaf(-2.f * S[2], S[2], 1.f);
    S[5] = S[4] * C[1] + C[4] * S[1];  C[5] = C[4] * C[1] - S[4] * S[1];
    S[6] = S[4] * C[2] + C[4] * S[2];  C[6] = C[4] * C[2] - S[4] * S[2];
    S[7] = S[4] * C[3] + C[4] * S[3];  C[7] = C[4] * C[3] - S[4] * S[3];
    S[8] = 2.f * S[4] * C[4];  C[8] = fmaf(-2.f * S[4], S[4], 1.f);
#pragma unroll
    for (int k = 1; k < 8; ++k) {
      S[8 + k] = S[8] * C[k] + C[8] * S[k];
      C[8 + k] = C[8] * C[k] - S[8] * S[k];
    }
    S[16] = 2.f * S[8] * C[8];  C[16] = fmaf(-2.f * S[8], S[8], 1.f);
#pragma unroll
    for (int c4 = 0; c4 < 4; ++c4) {
      H8 h;
#pragma unroll
      for (int q = 0; q < 4; ++q) {
        const int k = c4 * 4 + q + 1;
        h.h[2 * q] = (_Float16)S[k];  h.h[2 * q + 1] = (_Float16)C[k];
      }
      *(half8*)(dst + c4 * 8) = h.v;
    }
  };

  half8 B0[4], B1[4];
  auto loadB = [&](half8 (&Bt)[4], int s) {   // s = local substep index
    const size_t base = (size_t)(s * 2) * 512;
    Bt[0] = *(const half8*)(pb0 + base);
    Bt[1] = *(const half8*)(pb0 + base + 512);
    Bt[2] = *(const half8*)(pb1 + base);
    Bt[3] = *(const half8*)(pb1 + base + 512);
  };

  // prologue: A for phase 0 into buf0; x for phase 1; B for substep 0
  {
    const float xa0 = pxa[0], xb0 = pxb[0];
    genH(xa0, &As[0][gcw][grow][0]);
    genH(xb0, &As[0][gcw + 2][grow][0]);
  }
  float xa = pxa[(size_t)4 * B_ROWS], xb = pxb[(size_t)4 * B_ROWS];
  loadB(B0, 0);
  BAR();

#pragma unroll 1
  for (int p = 0; p < 64; ++p) {
    const int buf = p & 1;
    const int s = 4 * p;
    // x for phase p+2 (OOB-safe: worst case lands inside d_ws)
    const float xan = pxa[(size_t)(s + 8) * B_ROWS];
    const float xbn = pxb[(size_t)(s + 8) * B_ROWS];

    auto a_load = [&](half8 (&A)[4][2], int col) {
#pragma unroll
      for (int fr = 0; fr < 4; ++fr)
#pragma unroll
        for (int kcl = 0; kcl < 2; ++kcl)
          A[fr][kcl] = *(const half8*)&As[buf][col][fr * 32 + r32][(kcl * 2 + kh) * 8];
    };
    auto mfma_sub = [&](const half8 (&A)[4][2], const half8 (&Bt)[4]) {
      __builtin_amdgcn_s_setprio(1);
#pragma unroll
      for (int kcl = 0; kcl < 2; ++kcl)
#pragma unroll
        for (int fr = 0; fr < 4; ++fr)
#pragma unroll
          for (int fc = 0; fc < 2; ++fc)
            acc[fr][fc] = __builtin_amdgcn_mfma_f32_32x32x16_f16(
                A[fr][kcl], Bt[fc * 2 + kcl], acc[fr][fc], 0, 0, 0);
      __builtin_amdgcn_s_setprio(0);
    };

    half8 aX[4][2], aY[4][2];
    a_load(aX, 0);               // substep 0 frags
    a_load(aY, 1);               // substep 1 frags (depth-2 pipeline)
    loadB(B1, s + 1);
    mfma_sub(aX, B0);            // substep 0
    a_load(aX, 2);               // substep 2 frags (behind MFMA cluster)
    loadB(B0, s + 2);
    mfma_sub(aY, B1);            // substep 1
    a_load(aY, 3);               // substep 3 frags
    loadB(B1, s + 3);
    mfma_sub(aX, B0);            // substep 2
    if (p < 63) loadB(B0, s + 4);
    genH(xa, &As[buf ^ 1][gcw][grow][0]);       // A for phase p+1
    genH(xb, &As[buf ^ 1][gcw + 2][grow][0]);
    mfma_sub(aY, B1);            // substep 3
    BAR();                       // lgkm-only: B global loads stay in flight
    xa = xan; xb = xbn;
  }

  // epilogue: C/D 32x32 layout col=lane&31, row=(q&3)+8*(q>>2)+4*(lane>>5)
  float* dst;
  if (ATOMIC) dst = out;
  else dst = (kb == 0) ? out : part + (size_t)(kb - 1) * (B_ROWS * O_COLS);
#pragma unroll
  for (int fr = 0; fr < 4; ++fr)
#pragma unroll
    for (int fc = 0; fc < 2; ++fc)
#pragma unroll
      for (int q = 0; q < 16; ++q) {
        const int row = m0 + fr * 32 + (q & 3) + 8 * (q >> 2) + 4 * kh;
        const int col = o0 + wc * 64 + fc * 32 + r32;
        if (ATOMIC) atomicAdd(&dst[(size_t)row * O_COLS + col], acc[fr][fc][q]);
        else dst[(size_t)row * O_COLS + col] = acc[fr][fc][q];
      }
}

// ---------------------------------------------------------------------------
// Fallback (ws too small): direct-coef 16x16x32 path (no workspace).
// ---------------------------------------------------------------------------
__global__ __launch_bounds__(512, 4)
void fourier_gemm_direct(const float* __restrict__ x, const float* __restrict__ coef,
                         float* __restrict__ out) {
  __shared__ _Float16 Asd[128 * 64];
  __shared__ _Float16 Bsd[128 * 64];

  const int tid = threadIdx.x;
  const int lane = tid & 63;
  const int wave = tid >> 6;
  const int wr = wave >> 1;
  const int wcd = wave & 1;

  const int bid = blockIdx.x;
  const int o0 = (bid & 7) * 128;
  const int kb = (bid >> 3) & 1;
  const int m0 = (bid >> 4) * 128;

  const int rowA = tid >> 3;
  const int cch = tid & 7;
  const int cswz = cch ^ (rowA & 7);
  const int n1 = tid >> 3;
  const int c1q = tid & 7;
  const int r16 = lane & 15;
  const int kq = lane >> 4;

  float4v acc[2][4];
#pragma unroll
  for (int fr = 0; fr < 2; ++fr)
#pragma unroll
    for (int fc = 0; fc < 4; ++fc) acc[fr][fc] = (float4v){0.f, 0.f, 0.f, 0.f};

  float s1a[8], c1a[8], sa[8], ca[8];
  float s1b[8], c1b[8], sb[8], cb[8];

  const float* xa_base = x + (size_t)(m0 + rowA) * I_DIM + (size_t)kb * 512 + cch * 8;
  const float* xb_base = xa_base + (size_t)64 * I_DIM;

#pragma unroll 1
  for (int ib2 = 0; ib2 < 8; ++ib2) {
    {
      const float* xa = xa_base + ib2 * 64;
      const float* xb = xb_base + ib2 * 64;
      float xva[8], xvb[8];
      *(float4*)&xva[0] = *(const float4*)(xa);
      *(float4*)&xva[4] = *(const float4*)(xa + 4);
      *(float4*)&xvb[0] = *(const float4*)(xb);
      *(float4*)&xvb[4] = *(const float4*)(xb + 4);
#pragma unroll
      for (int e = 0; e < 8; ++e) {
        __sincosf(xva[e], &s1a[e], &c1a[e]); sa[e] = s1a[e]; ca[e] = c1a[e];
        __sincosf(xvb[e], &s1b[e], &c1b[e]); sb[e] = s1b[e]; cb[e] = c1b[e];
      }
    }
#pragma unroll 1
    for (int f = 0; f < NF33; ++f) {
      H8 ha, hb;
      if (f == 32) {
#pragma unroll
        for (int e = 0; e < 8; ++e) { ha.h[e] = (_Float16)1.0f; hb.h[e] = (_Float16)1.0f; }
      } else if ((f & 1) == 0) {
#pragma unroll
        for (int e = 0; e < 8; ++e) { ha.h[e] = (_Float16)sa[e]; hb.h[e] = (_Float16)sb[e]; }
      } else {
#pragma unroll
        for (int e = 0; e < 8; ++e) { ha.h[e] = (_Float16)ca[e]; hb.h[e] = (_Float16)cb[e]; }
      }
      __syncthreads();
      {
        const int ks = ksrc_of(f);
        const int ibg = kb * 8 + ib2;
        H8 b1, b2;
#pragma unroll
        for (int e = 0; e < 8; ++e) {
          const size_t ii = (size_t)(ibg * 64 + c1q * 8 + e) * NF33 + ks;
          b1.h[e] = (_Float16)coef[(size_t)(o0 + n1) * (I_DIM * NF33) + ii];
          b2.h[e] = (_Float16)coef[(size_t)(o0 + n1 + 64) * (I_DIM * NF33) + ii];
        }
        const int cs = (c1q ^ (n1 & 7)) << 3;
        *(half8*)&Bsd[n1 * 64 + cs] = b1.v;
        *(half8*)&Bsd[(n1 + 64) * 64 + cs] = b2.v;
      }
      *(half8*)&Asd[rowA * 64 + cswz * 8] = ha.v;
      *(half8*)&Asd[(rowA + 64) * 64 + cswz * 8] = hb.v;
      if ((f & 1) && (f + 2 < NF33)) {
#pragma unroll
        for (int e = 0; e < 8; ++e) {
          float ns = sa[e] * c1a[e] + ca[e] * s1a[e];
          ca[e] = ca[e] * c1a[e] - sa[e] * s1a[e]; sa[e] = ns;
          float nsb = sb[e] * c1b[e] + cb[e] * s1b[e];
          cb[e] = cb[e] * c1b[e] - sb[e] * s1b[e]; sb[e] = nsb;
        }
      }
      __syncthreads();
#pragma unroll
      for (int ksu = 0; ksu < 2; ++ksu) {
        const int ch = ((ksu << 2) + kq) ^ (r16 & 7);
        half8 af[2], bf[4];
#pragma unroll
        for (int fr = 0; fr < 2; ++fr)
          af[fr] = *(const half8*)&Asd[(wr * 32 + fr * 16 + r16) * 64 + ch * 8];
#pragma unroll
        for (int fc = 0; fc < 4; ++fc)
          bf[fc] = *(const half8*)&Bsd[(wcd * 64 + fc * 16 + r16) * 64 + ch * 8];
#pragma unroll
        for (int fr = 0; fr < 2; ++fr)
#pragma unroll
          for (int fc = 0; fc < 4; ++fc)
            acc[fr][fc] = __builtin_amdgcn_mfma_f32_16x16x32_f16(
                af[fr], bf[fc], acc[fr][fc], 0, 0, 0);
      }
    }
  }
#pragma unroll
  for (int fr = 0; fr < 2; ++fr)
#pragma unroll
    for (int fc = 0; fc < 4; ++fc)
#pragma unroll
      for (int r = 0; r < 4; ++r) {
        const int row = m0 + wr * 32 + fr * 16 + kq * 4 + r;
        const int col = o0 + wcd * 64 + fc * 16 + r16;
        atomicAdd(&out[(size_t)row * O_COLS + col], acc[fr][fc][r]);
      }
}

extern "C" void kernel_launch(void* const* d_in, const int* in_sizes, int n_in,
                              void* d_out, int out_size, void* d_ws, size_t ws_size,
                              hipStream_t stream) {
  const float* x = (const float*)d_in[0];
  const float* coef = (const float*)d_in[1];
  float* out = (float*)d_out;

  if (ws_size >= NEED_T1 || ws_size >= NEED_T2) {
    _Float16* Cw2 = (_Float16*)d_ws;
    float* xT   = (float*)((char*)d_ws + XT_OFF);
    float* bk   = (float*)((char*)d_ws + BK_OFF);
    float* bias = (float*)((char*)d_ws + BIAS_OFF);
    convert_coef2<<<dim3(4096), dim3(256), 0, stream>>>(coef, Cw2, bk);
    transpose_x<<<dim3(16, 64), dim3(256), 0, stream>>>(x, xT);
    bias_from_bk<<<dim3(4), dim3(256), 0, stream>>>(bk, bias);
    if (ws_size >= NEED_T1) {
      float* part = (float*)((char*)d_ws + PART_OFF);
      fourier_gemm9<false><<<dim3(512), dim3(256), 0, stream>>>(xT, Cw2, bias, out, part);
      reduce_parts<<<dim3(4096), dim3(256), 0, stream>>>(
          out, part, part + (size_t)B_ROWS * O_COLS, part + (size_t)2 * B_ROWS * O_COLS);
    } else {
      hipMemsetAsync(out, 0, (size_t)B_ROWS * O_COLS * sizeof(float), stream);
      fourier_gemm9<true><<<dim3(512), dim3(256), 0, stream>>>(xT, Cw2, bias, out, nullptr);
    }
  } else {
    hipMemsetAsync(out, 0, (size_t)B_ROWS * O_COLS * sizeof(float), stream);
    fourier_gemm_direct<<<dim3(512), dim3(512), 0, stream>>>(x, coef, out);
  }
}